// Round 5
// baseline (548.745 us; speedup 1.0000x reference)
//
#include <hip/hip_runtime.h>
#include <math.h>

#define ALPHA_ 0.1f
#define BETA_  0.9f
#define EPS_   1e-5f

typedef __bf16 bf16x8 __attribute__((ext_vector_type(8)));
typedef float f32x16 __attribute__((ext_vector_type(16)));

__device__ __forceinline__ unsigned short f2bf(float f) {
    return __builtin_bit_cast(unsigned short, (__bf16)f);
}
__device__ __forceinline__ float bf2f(unsigned short u) {
    return (float)__builtin_bit_cast(__bf16, u);
}

__device__ __forceinline__ float wave_reduce_sum(float v) {
#pragma unroll
    for (int off = 32; off > 0; off >>= 1) v += __shfl_down(v, off, 64);
    return v;
}

// ---------------- LN partial sums (per-b mean/var, stage 1) ----------------
__global__ void k_ln_part(const float4* __restrict__ x4, float2* __restrict__ part) {
    const int b = blockIdx.y, jb = blockIdx.x, t = threadIdx.x;
    const size_t base = (size_t)b * 307200 + (size_t)jb * 4096;
    float s = 0.f, sq = 0.f;
#pragma unroll
    for (int k = 0; k < 16; k++) {
        float4 v = x4[base + k * 256 + t];
        s  += v.x + v.y + v.z + v.w;
        sq += v.x * v.x + v.y * v.y + v.z * v.z + v.w * v.w;
    }
    float rs = wave_reduce_sum(s);
    float rq = wave_reduce_sum(sq);
    __shared__ float2 ws[4];
    if ((t & 63) == 0) ws[t >> 6] = make_float2(rs, rq);
    __syncthreads();
    if (t == 0) {
        float a = 0.f, q = 0.f;
        for (int k = 0; k < 4; k++) { a += ws[k].x; q += ws[k].y; }
        part[b * 75 + jb] = make_float2(a, q);
    }
}

__global__ void k_ln_final(const float2* __restrict__ part, int nper, float2* __restrict__ outp) {
    const int b = blockIdx.x, t = threadIdx.x;
    float s = 0.f, sq = 0.f;
    for (int p = t; p < nper; p += 64) {
        float2 v = part[b * nper + p];
        s += v.x; sq += v.y;
    }
    s  = wave_reduce_sum(s);
    sq = wave_reduce_sum(sq);
    if (t == 0) {
        const float invN = 1.f / 1228800.f;
        float mu  = s * invN;
        float var = sq * invN - mu * mu;
        outp[b] = make_float2(mu, rsqrtf(var + EPS_));
    }
}

// ---------------- xw = LN1(x) @ Wih^T + bih  (MFMA bf16, bf16 output) ----------------
__global__ __launch_bounds__(256) void k_xw2(const float* __restrict__ x,
        const float* __restrict__ g1, const float* __restrict__ b1,
        const float2* __restrict__ s1, const float* __restrict__ Wih,
        const float* __restrict__ bih, unsigned short* __restrict__ xw) {
    __shared__ unsigned short sXb[128 * 64];
    __shared__ unsigned short sWb[192 * 64];
    const int t = threadIdx.x;
    const int R0 = blockIdx.x * 128;
    const float2 st1 = s1[R0 / 19200];
    for (int idx = t; idx < 8192; idx += 256) {
        int rr = idx >> 6, cc = idx & 63;
        int row = R0 + rr;
        int gi = (row % 19200) * 64 + cc;
        float v = (x[(size_t)row * 64 + cc] - st1.x) * st1.y * g1[gi] + b1[gi];
        *(unsigned short*)((char*)sXb + ((rr * 128 + cc * 2) ^ ((rr & 7) << 4))) = f2bf(v);
    }
    for (int idx = t; idx < 12288; idx += 256) {
        int j = idx >> 6, k = idx & 63;
        *(unsigned short*)((char*)sWb + ((j * 128 + k * 2) ^ ((j & 7) << 4))) = f2bf(Wih[idx]);
    }
    __syncthreads();
    const int wid = t >> 6, lane = t & 63, ln = lane & 31, hl = lane >> 5;
    f32x16 acc[6] = {};
#pragma unroll
    for (int ks = 0; ks < 4; ks++) {
        int ao = ((wid * 32 + ln) * 128 + ks * 32 + hl * 16) ^ ((ln & 7) << 4);
        bf16x8 af = __builtin_bit_cast(bf16x8, *(const uint4*)((const char*)sXb + ao));
#pragma unroll
        for (int nt = 0; nt < 6; nt++) {
            int bo = ((nt * 32 + ln) * 128 + ks * 32 + hl * 16) ^ ((ln & 7) << 4);
            bf16x8 bfr = __builtin_bit_cast(bf16x8, *(const uint4*)((const char*)sWb + bo));
            acc[nt] = __builtin_amdgcn_mfma_f32_32x32x16_bf16(af, bfr, acc[nt], 0, 0, 0);
        }
    }
#pragma unroll
    for (int nt = 0; nt < 6; nt++) {
        float bi = bih[nt * 32 + ln];
#pragma unroll
        for (int reg = 0; reg < 16; reg++) {
            int rrow = (reg & 3) + 8 * (reg >> 2) + 4 * hl;
            int row = R0 + wid * 32 + rrow;
            xw[(size_t)row * 192 + nt * 32 + ln] = f2bf(acc[nt][reg] + bi);
        }
    }
}

// ---------------- persistent GRU, MFMA recurrence, weights in registers ----------------
__global__ __launch_bounds__(512) void k_gru2(const unsigned short* __restrict__ xw,
        const float* __restrict__ x, const float* __restrict__ Whh,
        const float* __restrict__ bhh, float* __restrict__ xr, float2* __restrict__ s2p) {
    __shared__ unsigned short hb[2048];      // [32][64] bf16, XOR-swizzled; rows 8..31 = 0
    __shared__ float gh[1536];               // [8][192]
    __shared__ float2 sRed[8];
    const int t = threadIdx.x;
    const int wid = t >> 6, lane = t & 63, ln = lane & 31, hl = lane >> 5;
    const int row0 = blockIdx.x * 8;
    const int r = wid;
    const int c = t & 63;

    bf16x8 Bf[4];
    if (wid < 6) {
        const int j = wid * 32 + ln;
#pragma unroll
        for (int ks = 0; ks < 4; ks++) {
            const float* wp = Whh + j * 64 + ks * 16 + hl * 8;
            float4 w0 = *(const float4*)wp;
            float4 w1 = *(const float4*)(wp + 4);
            bf16x8 bb;
            bb[0] = (__bf16)w0.x; bb[1] = (__bf16)w0.y; bb[2] = (__bf16)w0.z; bb[3] = (__bf16)w0.w;
            bb[4] = (__bf16)w1.x; bb[5] = (__bf16)w1.y; bb[6] = (__bf16)w1.z; bb[7] = (__bf16)w1.w;
            Bf[ks] = bb;
        }
    }
    for (int i = t; i < 2048; i += 512) hb[i] = 0;

    const float b_r = bhh[c], b_z = bhh[64 + c], b_n = bhh[128 + c];
    const unsigned short* xwp = xw + (size_t)(row0 + r) * 96 * 192;
    const float* xp  = x  + (size_t)(row0 + r) * 96 * 64;
    float*       xrp = xr + (size_t)(row0 + r) * 96 * 64;
    float xg = bf2f(xwp[c]), zg = bf2f(xwp[64 + c]), ng = bf2f(xwp[128 + c]);
    float xv = xp[c];
    float h = 0.f, lsum = 0.f, lsq = 0.f;
    __syncthreads();

    for (int st = 0; st < 96; st++) {
        if (wid < 6) {
            f32x16 acc = {};
#pragma unroll
            for (int ks = 0; ks < 4; ks++) {
                int ao = (ln * 128 + ks * 32 + hl * 16) ^ ((ln & 7) << 4);
                bf16x8 af = __builtin_bit_cast(bf16x8, *(const uint4*)((const char*)hb + ao));
                acc = __builtin_amdgcn_mfma_f32_32x32x16_bf16(af, Bf[ks], acc, 0, 0, 0);
            }
#pragma unroll
            for (int reg = 0; reg < 4; reg++) {
                gh[(reg + 4 * hl) * 192 + wid * 32 + ln] = acc[reg];
            }
        }
        __syncthreads();
        float hr_ = gh[r * 192 + c] + b_r;
        float hz  = gh[r * 192 + 64 + c] + b_z;
        float hn  = gh[r * 192 + 128 + c] + b_n;
        float rg_ = 1.f / (1.f + __expf(-(xg + hr_)));
        float zg_ = 1.f / (1.f + __expf(-(zg + hz)));
        float ny = ng + rg_ * hn;
        ny = fminf(fmaxf(ny, -15.f), 15.f);
        float e2 = __expf(-2.f * ny);
        float nv = (1.f - e2) / (1.f + e2);
        h = nv + zg_ * (h - nv);
        float ov = h + xv;
        xrp[st * 64 + c] = ov;
        lsum += ov; lsq += ov * ov;
        *(unsigned short*)((char*)hb + ((r * 128 + c * 2) ^ ((r & 7) << 4))) = f2bf(h);
        int sn = st < 95 ? st + 1 : 95;
        xg = bf2f(xwp[sn * 192 + c]); zg = bf2f(xwp[sn * 192 + 64 + c]); ng = bf2f(xwp[sn * 192 + 128 + c]);
        xv = xp[sn * 64 + c];
        __syncthreads();
    }
    float s = wave_reduce_sum(lsum);
    float q = wave_reduce_sum(lsq);
    if (lane == 0) sRed[wid] = make_float2(s, q);
    __syncthreads();
    if (t == 0) {
        float a = 0.f, b_ = 0.f;
        for (int k = 0; k < 8; k++) { a += sRed[k].x; b_ += sRed[k].y; }
        s2p[blockIdx.x] = make_float2(a, b_);
    }
}

// ---------------- transpose g2/b2: [64][200][96] -> [96][200][64] ----------------
__global__ void k_tr(const float* __restrict__ in, float* __restrict__ outp) {
    __shared__ float tile[32][33];
    const int v = blockIdx.x;
    const int ct = blockIdx.y & 1;
    const int lt = blockIdx.y >> 1;
    const int t = threadIdx.x;
    const int lx = t & 31, ly = t >> 5;
    const int c0 = ct * 32, l0 = lt * 32;
#pragma unroll
    for (int q = 0; q < 4; q++) {
        int cc = ly + q * 8;
        tile[cc][lx] = in[(size_t)(c0 + cc) * 19200 + (size_t)v * 96 + l0 + lx];
    }
    __syncthreads();
#pragma unroll
    for (int q = 0; q < 4; q++) {
        int ll = ly + q * 8;
        outp[(size_t)(l0 + ll) * 12800 + (size_t)v * 64 + c0 + lx] = tile[lx][ll];
    }
}

// ---------------- static adjacency -> normalized bf16, padded [224][208] ----------------
__global__ void k_adjprep(const float* __restrict__ adj, unsigned short* __restrict__ an_b,
        unsigned short* __restrict__ atn_b) {
    const int v = blockIdx.x;
    const int mode = blockIdx.y;
    const int t = threadIdx.x;
    unsigned short* outp = (mode == 0) ? an_b : atn_b;
    if (v >= 200) { if (t < 208) outp[v * 208 + t] = 0; return; }
    float val = 0.f;
    if (t < 200) val = (mode == 0) ? adj[v * 200 + t] : adj[t * 200 + v];
    float s = wave_reduce_sum(val);
    __shared__ float sp[4];
    if ((t & 63) == 0) sp[t >> 6] = s;
    __syncthreads();
    float inv = 1.f / (sp[0] + sp[1] + sp[2] + sp[3] + 1.f);
    if (t < 208) {
        float o = (t < 200) ? (val + (t == v ? 1.f : 0.f)) * inv : 0.f;
        outp[v * 208 + t] = f2bf(o);
    }
}

// ---------------- fused dyna prep: read once, transpose in LDS, write both orientations ----------------
__global__ __launch_bounds__(256) void k_dprep2(const float* __restrict__ dyna,
        unsigned short* __restrict__ danr, unsigned short* __restrict__ danc) {
    __shared__ unsigned short sT[200 * 201];   // [c][r] bf16 of S[r][c] (+diag), 80400 B
    __shared__ unsigned short sInv[416];       // [0..199]=irs bf16, [208..407]=ics bf16
    const int blk = blockIdx.x;
    const int t = threadIdx.x;
    const int lane = t & 63, rq = t >> 6;
    const float* S = dyna + (size_t)blk * 40000;
    // phase 1: read S once (coalesced), store transposed bf16 with diag folded
    for (int p = 0; p < 50; p++) {
        const int r = p * 4 + rq;
#pragma unroll
        for (int s = 0; s < 4; s++) {
            const int c = s * 64 + lane;
            if (c < 200) {
                float v = S[r * 200 + c] + ((r == c) ? 1.f : 0.f);
                sT[c * 201 + r] = f2bf(v);
            }
        }
    }
    __syncthreads();
    // phase 2: sums from the tile (diag already included -> denominators directly)
    if (t < 200) {
        float cs = 0.f;
        for (int rr = 0; rr < 200; rr++) cs += bf2f(sT[t * 201 + rr]);
        sInv[208 + t] = f2bf(1.f / cs);
        float rs = 0.f;
        for (int cc = 0; cc < 200; cc++) rs += bf2f(sT[cc * 201 + t]);
        sInv[t] = f2bf(1.f / rs);
    }
    __syncthreads();
    // phase 3: write danr / danc (coalesced u16 rows)
    unsigned short* dr = danr + (size_t)blk * 41600;
    unsigned short* dc = danc + (size_t)blk * 41600;
    for (int p = 0; p < 50; p++) {
        const int w = p * 4 + rq;
        const float icw = bf2f(sInv[208 + w]);
        const float irw = bf2f(sInv[w]);
#pragma unroll
        for (int s = 0; s < 4; s++) {
            const int r2 = s * 64 + lane;
            if (r2 < 200) {
                dc[w * 208 + r2] = f2bf(bf2f(sT[w * 201 + r2]) * icw);
                dr[w * 208 + r2] = f2bf(bf2f(sT[r2 * 201 + w]) * irw);
            }
        }
    }
    if (blk == 767) {
        for (int idx = t; idx < 4992; idx += 256) {
            danr[(size_t)768 * 41600 + idx] = 0;
            danc[(size_t)768 * 41600 + idx] = 0;
        }
    }
}

// ---------------- effective projection matrices -> bf16 MeffB[9][64][64] + biasE ----------------
__global__ void k_meff(const float* __restrict__ Wm, const float* __restrict__ Wg1,
        const float* __restrict__ Wg2, const float* __restrict__ Wd1, const float* __restrict__ Wd2,
        const float* __restrict__ bg1, const float* __restrict__ bg2, const float* __restrict__ bd1,
        const float* __restrict__ bd2, const float* __restrict__ bm,
        unsigned short* __restrict__ MeffB, float* __restrict__ biasE) {
    const int k = blockIdx.x;
    const int t = threadIdx.x;
    const int o = t >> 2;
    const int cb = (t & 3) * 16;
    float acc[16];
#pragma unroll
    for (int q = 0; q < 16; q++) acc[q] = 0.f;
    if (k == 0) {
        for (int m = 0; m < 64; m++) {
            float aL = Wm[o * 128 + m], aR = Wm[o * 128 + 64 + m];
#pragma unroll
            for (int q = 0; q < 16; q++) {
                int cc = cb + q;
                acc[q] += aL * (Wg1[m * 192 + cc] + Wg2[m * 192 + cc])
                        + aR * (Wd1[m * 192 + cc] + Wd2[m * 192 + cc]);
            }
        }
    } else {
        const float* Ws = (k <= 2) ? Wg1 : (k <= 4) ? Wg2 : (k <= 6) ? Wd1 : Wd2;
        const int side = (k <= 4) ? 0 : 64;
        const int hop = (((k - 1) & 1) == 0) ? 64 : 128;
        for (int m = 0; m < 64; m++) {
            float a_ = Wm[o * 128 + side + m];
#pragma unroll
            for (int q = 0; q < 16; q++) acc[q] += a_ * Ws[m * 192 + hop + cb + q];
        }
    }
#pragma unroll
    for (int q = 0; q < 16; q++) MeffB[k * 4096 + o * 64 + cb + q] = f2bf(acc[q]);
    if (k == 0 && t < 64) {
        float s = bm[t];
        for (int cc = 0; cc < 64; cc++)
            s += Wm[t * 128 + cc] * (bg1[cc] + bg2[cc]) + Wm[t * 128 + 64 + cc] * (bd1[cc] + bd2[cc]);
        biasE[t] = s;
    }
}

// ---------------- nx (bf16) = LN2(xr), layout [b*96+l][v][c] ----------------
__global__ void k_nx(const float4* __restrict__ xr4, const float2* __restrict__ s2,
        const float4* __restrict__ g2t4, const float4* __restrict__ b2t4,
        unsigned short* __restrict__ nxb) {
    size_t id = (size_t)blockIdx.x * 256 + threadIdx.x;
    int cf = (int)(id & 15);
    size_t grp = id >> 4;
    int v = (int)(grp % 200);
    size_t bl = grp / 200;
    int l = (int)(bl % 96);
    int b = (int)(bl / 96);
    float2 st = s2[b];
    float4 xv = xr4[(((size_t)(b * 200 + v)) * 96 + l) * 16 + cf];
    size_t gi = ((size_t)l * 200 + v) * 16 + cf;
    float4 g = g2t4[gi];
    float4 bb = b2t4[gi];
    unsigned int lo = (unsigned)f2bf((xv.x - st.x) * st.y * g.x + bb.x)
                    | ((unsigned)f2bf((xv.y - st.x) * st.y * g.y + bb.y) << 16);
    unsigned int hi = (unsigned)f2bf((xv.z - st.x) * st.y * g.z + bb.z)
                    | ((unsigned)f2bf((xv.w - st.x) * st.y * g.w + bb.w) << 16);
    ((uint2*)nxb)[id] = make_uint2(lo, hi);
}

// ================= MFMA graph kernel v3 =================
#define OFF_HT0 0
#define OFF_H0R 32768
#define OFF_HT1 61440
#define OFF_H1R 94208
#define OFF_H2R 122880
#define OFF_OBUF 61440
#define SMEM_SZ 151552

__device__ __forceinline__ int ht_addr(int c, int w) {
    return (c * 512 + w * 2) ^ (((c >> 2) & 7) << 4);
}
__device__ __forceinline__ int hr_addr(int v, int c) {
    return (v * 128 + c * 2) ^ ((v & 7) << 4);
}

// prop with A cached in regs + h0 cached packed in regs
__device__ __forceinline__ void prop_core(unsigned char* smem,
        const uint4 (&Ar0)[13], const uint4 (&Ar1)[13], bool has2,
        const unsigned int (&h0p)[16],
        int srcHt, int dstHt, int dstHr, int wid, int ln, int half) {
    const int ct = wid & 1;
    const int mt0 = wid >> 1;
    const int c = ct * 32 + ln;
    f32x16 acc0 = {}; f32x16 acc1 = {};
#pragma unroll
    for (int kk = 0; kk < 13; kk++) {
        const int k0 = kk * 16 + half * 8;
        bf16x8 bf = __builtin_bit_cast(bf16x8, *(const uint4*)(smem + srcHt + ht_addr(c, k0)));
        acc0 = __builtin_amdgcn_mfma_f32_32x32x16_bf16(
            __builtin_bit_cast(bf16x8, Ar0[kk]), bf, acc0, 0, 0, 0);
        if (has2)
            acc1 = __builtin_amdgcn_mfma_f32_32x32x16_bf16(
                __builtin_bit_cast(bf16x8, Ar1[kk]), bf, acc1, 0, 0, 0);
    }
    // store tile 0
#pragma unroll
    for (int g = 0; g < 4; g++) {
        const int vb = mt0 * 32 + half * 4 + g * 8;
        if (vb < 200) {
            unsigned short pk[4];
#pragma unroll
            for (int p = 0; p < 2; p++) {
                unsigned int hp = h0p[g * 2 + p];
                float hna = ALPHA_ * bf2f((unsigned short)(hp & 0xffffu)) + BETA_ * acc0[g * 4 + 2 * p];
                float hnb = ALPHA_ * bf2f((unsigned short)(hp >> 16)) + BETA_ * acc0[g * 4 + 2 * p + 1];
                unsigned short ba = f2bf(hna), bb = f2bf(hnb);
                pk[2 * p] = ba; pk[2 * p + 1] = bb;
                *(unsigned short*)(smem + dstHr + hr_addr(vb + 2 * p, c)) = ba;
                *(unsigned short*)(smem + dstHr + hr_addr(vb + 2 * p + 1, c)) = bb;
            }
            if (dstHt >= 0) {
                *(uint2*)(smem + dstHt + ht_addr(c, vb)) = make_uint2(
                    (unsigned)pk[0] | ((unsigned)pk[1] << 16),
                    (unsigned)pk[2] | ((unsigned)pk[3] << 16));
            }
        }
    }
    if (has2) {
#pragma unroll
        for (int g = 0; g < 4; g++) {
            const int vb = (mt0 + 4) * 32 + half * 4 + g * 8;
            if (vb < 200) {
                unsigned short pk[4];
#pragma unroll
                for (int p = 0; p < 2; p++) {
                    unsigned int hp = h0p[8 + g * 2 + p];
                    float hna = ALPHA_ * bf2f((unsigned short)(hp & 0xffffu)) + BETA_ * acc1[g * 4 + 2 * p];
                    float hnb = ALPHA_ * bf2f((unsigned short)(hp >> 16)) + BETA_ * acc1[g * 4 + 2 * p + 1];
                    unsigned short ba = f2bf(hna), bb = f2bf(hnb);
                    pk[2 * p] = ba; pk[2 * p + 1] = bb;
                    *(unsigned short*)(smem + dstHr + hr_addr(vb + 2 * p, c)) = ba;
                    *(unsigned short*)(smem + dstHr + hr_addr(vb + 2 * p + 1, c)) = bb;
                }
                if (dstHt >= 0) {
                    *(uint2*)(smem + dstHt + ht_addr(c, vb)) = make_uint2(
                        (unsigned)pk[0] | ((unsigned)pk[1] << 16),
                        (unsigned)pk[2] | ((unsigned)pk[3] << 16));
                }
            }
        }
    }
}

// projection: D[m=v][n=o] = mfma(A=Hr rows, B=Meff rows)
__device__ __forceinline__ void proj_step(unsigned char* smem, const unsigned short* __restrict__ MB,
        int srcHr, int wid, int ln, int half, f32x16& A0, f32x16& A1) {
    const int ot = wid & 1;
    const int vt0 = wid >> 1;
    const bool has2 = (wid < 6);
    const int o = ot * 32 + ln;
    const int va = vt0 * 32 + ln;
    const int vb = (vt0 + 4) * 32 + ln;
#pragma unroll
    for (int kk = 0; kk < 4; kk++) {
        const int c0 = kk * 16 + half * 8;
        bf16x8 mf = __builtin_bit_cast(bf16x8, *(const uint4*)(const void*)(MB + o * 64 + c0));
        bf16x8 h0 = __builtin_bit_cast(bf16x8, *(const uint4*)(smem + srcHr + hr_addr(va, c0)));
        A0 = __builtin_amdgcn_mfma_f32_32x32x16_bf16(h0, mf, A0, 0, 0, 0);
        if (has2) {
            bf16x8 h1 = __builtin_bit_cast(bf16x8, *(const uint4*)(smem + srcHr + hr_addr(vb, c0)));
            A1 = __builtin_amdgcn_mfma_f32_32x32x16_bf16(h1, mf, A1, 0, 0, 0);
        }
    }
}

__device__ __forceinline__ void store_obuf(unsigned char* smem, const f32x16& acc, int vt, int ot,
        int ln, int half) {
#pragma unroll
    for (int r = 0; r < 16; r++) {
        const int v = vt * 32 + half * 4 + (r & 3) + (r >> 2) * 8;
        if (v < 200) *(float*)(smem + OFF_OBUF + (v * 64 + ot * 32 + ln) * 4) = acc[r];
    }
}

__global__ __launch_bounds__(512, 2) void k_graph3(const unsigned short* __restrict__ nxb,
        const float* __restrict__ xrb, const unsigned short* __restrict__ an_b,
        const unsigned short* __restrict__ atn_b, const unsigned short* __restrict__ danr_b,
        const unsigned short* __restrict__ danc_b, const unsigned short* __restrict__ MeffB,
        const float* __restrict__ biasE, float* __restrict__ out) {
    __shared__ __align__(16) unsigned char smem[SMEM_SZ];
    const int blk = blockIdx.x;
    const int b = blk / 96, l = blk % 96;
    const int t = threadIdx.x;
    const int wid = t >> 6, lane = t & 63, ln = lane & 31, half = lane >> 5;

    const unsigned int* nxs = (const unsigned int*)(nxb + (size_t)blk * 12800);
    for (int idx = t; idx < 6400; idx += 512) {
        unsigned int val = nxs[idx];
        int v = idx >> 5, c2 = (idx & 31) * 2;
        *(unsigned int*)(smem + OFF_H0R + hr_addr(v, c2)) = val;
        *(unsigned short*)(smem + OFF_HT0 + ht_addr(c2, v)) = (unsigned short)(val & 0xffffu);
        *(unsigned short*)(smem + OFF_HT0 + ht_addr(c2 + 1, v)) = (unsigned short)(val >> 16);
    }
    for (int idx = t; idx < 768; idx += 512) {
        int v = 200 + (idx >> 5), c2 = (idx & 31) * 2;
        *(unsigned int*)(smem + OFF_H0R + hr_addr(v, c2)) = 0;
    }
    if (t < 512) {
        int c = t >> 3, w = 200 + (t & 7);
        *(unsigned short*)(smem + OFF_HT0 + ht_addr(c, w)) = 0;
        *(unsigned short*)(smem + OFF_HT1 + ht_addr(c, w)) = 0;
    }
    __syncthreads();

    const bool has2 = (wid < 6);
    const int mt0 = wid >> 1;
    const int cprop = (wid & 1) * 32 + ln;

    // h0 packed cache (per-lane (v,c) pairs used by prop_store; rows 200..223 of H0R are zeroed)
    unsigned int h0p[16];
#pragma unroll
    for (int g = 0; g < 4; g++) {
#pragma unroll
        for (int p = 0; p < 2; p++) {
            int v = mt0 * 32 + half * 4 + g * 8 + 2 * p;
            unsigned short a_ = *(const unsigned short*)(smem + OFF_H0R + hr_addr(v, cprop));
            unsigned short b_ = *(const unsigned short*)(smem + OFF_H0R + hr_addr(v + 1, cprop));
            h0p[g * 2 + p] = (unsigned)a_ | ((unsigned)b_ << 16);
        }
    }
    if (has2) {
#pragma unroll
        for (int g = 0; g < 4; g++) {
#pragma unroll
            for (int p = 0; p < 2; p++) {
                int v = (mt0 + 4) * 32 + half * 4 + g * 8 + 2 * p;
                unsigned short a_ = *(const unsigned short*)(smem + OFF_H0R + hr_addr(v, cprop));
                unsigned short b_ = *(const unsigned short*)(smem + OFF_H0R + hr_addr(v + 1, cprop));
                h0p[8 + g * 2 + p] = (unsigned)a_ | ((unsigned)b_ << 16);
            }
        }
    } else {
#pragma unroll
        for (int q = 0; q < 8; q++) h0p[8 + q] = 0;
    }

    f32x16 ACC0 = {}; f32x16 ACC1 = {};
    proj_step(smem, MeffB, OFF_H0R, wid, ln, half, ACC0, ACC1);

#pragma unroll 1
    for (int chain = 0; chain < 4; chain++) {
        const unsigned short* A = (chain == 0) ? an_b : (chain == 1) ? atn_b
            : (chain == 2) ? (danr_b + (size_t)blk * 41600) : (danc_b + (size_t)blk * 41600);
        // cache A rows for this chain in registers (used by both hops)
        uint4 Ar0[13], Ar1[13];
        const unsigned short* A0p = A + (size_t)(mt0 * 32 + ln) * 208;
        const unsigned short* A1p = A + (size_t)((mt0 + 4) * 32 + ln) * 208;
#pragma unroll
        for (int kk = 0; kk < 13; kk++) {
            const int k0 = kk * 16 + half * 8;
            Ar0[kk] = *(const uint4*)(const void*)(A0p + k0);
            if (has2) Ar1[kk] = *(const uint4*)(const void*)(A1p + k0);
        }
        prop_core(smem, Ar0, Ar1, has2, h0p, OFF_HT0, OFF_HT1, OFF_H1R, wid, ln, half);
        __syncthreads();
        proj_step(smem, MeffB + (size_t)(1 + 2 * chain) * 4096, OFF_H1R, wid, ln, half, ACC0, ACC1);
        prop_core(smem, Ar0, Ar1, has2, h0p, OFF_HT1, -1, OFF_H2R, wid, ln, half);
        __syncthreads();
        proj_step(smem, MeffB + (size_t)(2 + 2 * chain) * 4096, OFF_H2R, wid, ln, half, ACC0, ACC1);
    }

    {
        const int ot = wid & 1, vt0 = wid >> 1;
        store_obuf(smem, ACC0, vt0, ot, ln, half);
        if (has2) store_obuf(smem, ACC1, vt0 + 4, ot, ln, half);
    }
    __syncthreads();

    const size_t gbase = ((size_t)b * 200 * 96 + l) * 64;
    for (int idx = t; idx < 12800; idx += 512) {
        int v = idx >> 6, o = idx & 63;
        float val = *(const float*)(smem + OFF_OBUF + idx * 4) + biasE[o];
        size_t gi = gbase + (size_t)v * 6144 + o;
        out[gi] = val + xrb[gi];
    }
}

extern "C" void kernel_launch(void* const* d_in, const int* in_sizes, int n_in,
                              void* d_out, int out_size, void* d_ws, size_t ws_size,
                              hipStream_t stream) {
    (void)in_sizes; (void)n_in; (void)out_size; (void)ws_size;
    const float* x    = (const float*)d_in[0];
    const float* adj  = (const float*)d_in[1];
    const float* dyna = (const float*)d_in[2];
    const float* g1   = (const float*)d_in[3];
    const float* b1   = (const float*)d_in[4];
    const float* g2   = (const float*)d_in[5];
    const float* b2   = (const float*)d_in[6];
    const float* Wih  = (const float*)d_in[7];
    const float* Whh  = (const float*)d_in[8];
    const float* bih  = (const float*)d_in[9];
    const float* bhh  = (const float*)d_in[10];
    const float* Wg1  = (const float*)d_in[11];
    const float* bg1  = (const float*)d_in[12];
    const float* Wg2  = (const float*)d_in[13];
    const float* bg2  = (const float*)d_in[14];
    const float* Wd1  = (const float*)d_in[15];
    const float* bd1  = (const float*)d_in[16];
    const float* Wd2  = (const float*)d_in[17];
    const float* bd2  = (const float*)d_in[18];
    const float* Wm   = (const float*)d_in[19];
    const float* bm   = (const float*)d_in[20];
    float* out = (float*)d_out;
    float* ws = (float*)d_ws;

    float*          xr    = ws;                                   // 9,830,400
    unsigned short* nxb   = (unsigned short*)(ws + 9830400);      // 9,830,400 bf16
    float*          g2t   = ws + 14745600;                        // 1,228,800
    float*          b2t   = ws + 15974400;                        // 1,228,800
    unsigned short* an_b  = (unsigned short*)(ws + 17203200);     // 224*208 bf16
    unsigned short* atn_b = (unsigned short*)(ws + 17226496);     // 224*208 bf16
    unsigned short* MeffB = (unsigned short*)(ws + 17249792);     // 9*64*64 bf16
    float*          biasE = ws + 17268224;                        // 64
    float2*         s1p   = (float2*)(ws + 17268288);             // 600 float2
    float2*         s1    = (float2*)(ws + 17269488);             // 8
    float2*         s2p   = (float2*)(ws + 17269504);             // 200
    float2*         s2    = (float2*)(ws + 17269904);             // 8
    // big region: xw bf16 (phase A), then danr/danc bf16 (phase B, after k_gru2)
    unsigned short* xwb    = (unsigned short*)(ws + 17269920);    // 29,491,200 u16
    unsigned short* danr_b = (unsigned short*)(ws + 17269920);    // 768*41600+4992 u16
    unsigned short* danc_b = danr_b + 31953792;

    k_ln_part<<<dim3(75, 8), dim3(256), 0, stream>>>((const float4*)x, s1p);
    k_ln_final<<<dim3(8), dim3(64), 0, stream>>>(s1p, 75, s1);
    k_xw2<<<dim3(1200), dim3(256), 0, stream>>>(x, g1, b1, s1, Wih, bih, xwb);
    k_gru2<<<dim3(200), dim3(512), 0, stream>>>(xwb, x, Whh, bhh, xr, s2p);
    k_ln_final<<<dim3(8), dim3(64), 0, stream>>>(s2p, 25, s2);
    k_tr<<<dim3(200, 6), dim3(256), 0, stream>>>(g2, g2t);
    k_tr<<<dim3(200, 6), dim3(256), 0, stream>>>(b2, b2t);
    k_adjprep<<<dim3(224, 2), dim3(256), 0, stream>>>(adj, an_b, atn_b);
    k_meff<<<dim3(9), dim3(256), 0, stream>>>(Wm, Wg1, Wg2, Wd1, Wd2, bg1, bg2, bd1, bd2, bm, MeffB, biasE);
    k_nx<<<dim3(9600), dim3(256), 0, stream>>>((const float4*)xr, s2, (const float4*)g2t, (const float4*)b2t, nxb);
    k_dprep2<<<dim3(768), dim3(256), 0, stream>>>(dyna, danr_b, danc_b);  // after k_gru2 (reuses xw region)
    k_graph3<<<dim3(768), dim3(512), 0, stream>>>(nxb, xr, an_b, atn_b, danr_b, danc_b, MeffB, biasE, out);
}